// Round 1
// baseline (292.113 us; speedup 1.0000x reference)
//
#include <hip/hip_runtime.h>

#define NCLS 18

__global__ __launch_bounds__(256) void ce_soft_kernel(
    const float* __restrict__ logits,
    const float* __restrict__ labels,
    float* __restrict__ result,
    int B, float invB)
{
    int tid = blockIdx.x * blockDim.x + threadIdx.x;
    int stride = gridDim.x * blockDim.x;

    float acc = 0.0f;
    for (int row = tid; row < B; row += stride) {
        // 72-byte rows: 8-byte aligned always -> float2 loads are safe.
        const float2* o2 = (const float2*)(logits + (size_t)row * NCLS);
        const float2* l2 = (const float2*)(labels + (size_t)row * NCLS);
        float x[NCLS], l[NCLS];
        #pragma unroll
        for (int k = 0; k < NCLS / 2; ++k) {
            float2 v = o2[k];
            x[2 * k] = v.x; x[2 * k + 1] = v.y;
        }
        #pragma unroll
        for (int k = 0; k < NCLS / 2; ++k) {
            float2 w = l2[k];
            l[2 * k] = w.x; l[2 * k + 1] = w.y;
        }

        float m = x[0];
        #pragma unroll
        for (int c = 1; c < NCLS; ++c) m = fmaxf(m, x[c]);

        float se = 0.0f, dot = 0.0f, sl = 0.0f;
        #pragma unroll
        for (int c = 0; c < NCLS; ++c) {
            se += __expf(x[c] - m);
            dot = fmaf(l[c], x[c], dot);
            sl += l[c];
        }
        float lse = m + __logf(se);
        // per_row = -sum_c l_c * (x_c - lse) = sl*lse - dot
        acc = fmaf(sl, lse, acc - dot);
    }

    // wave (64-lane) shuffle reduction
    #pragma unroll
    for (int off = 32; off > 0; off >>= 1)
        acc += __shfl_down(acc, off, 64);

    __shared__ float wave_sums[4];
    int lane = threadIdx.x & 63;
    int wid  = threadIdx.x >> 6;
    if (lane == 0) wave_sums[wid] = acc;
    __syncthreads();
    if (threadIdx.x == 0) {
        float s = wave_sums[0] + wave_sums[1] + wave_sums[2] + wave_sums[3];
        atomicAdd(result, s * invB);
    }
}

extern "C" void kernel_launch(void* const* d_in, const int* in_sizes, int n_in,
                              void* d_out, int out_size, void* d_ws, size_t ws_size,
                              hipStream_t stream) {
    const float* logits = (const float*)d_in[0];
    const float* labels = (const float*)d_in[1];
    float* result = (float*)d_out;

    int B = in_sizes[0] / NCLS;   // 2,000,000

    // d_out is poisoned with 0xAA before every launch; zero it for the atomic.
    hipMemsetAsync(d_out, 0, sizeof(float), stream);

    int block = 256;
    int grid  = 2048;             // 524288 threads, ~3.8 rows/thread, 256 CUs saturated
    ce_soft_kernel<<<grid, block, 0, stream>>>(logits, labels, result, B, 1.0f / (float)B);
}